// Round 7
// baseline (903.039 us; speedup 1.0000x reference)
//
#include <hip/hip_runtime.h>
#include <hip/hip_bf16.h>
#include <hip/hip_cooperative_groups.h>

namespace cg = cooperative_groups;

// GCN: 3 layers of  h = h + relu( segment_sum( norm * (h@W^T+b)[row], col ) )
// norm[e] = dis[row]*dis[col]*(row!=col), dis[v] = deg_row(v)>0 ? rsqrt(deg) : 0
// N=50000, D=128, E=800000. Harness compares in bf16 space (threshold 0.108):
// hW / GEMM inputs carried in bf16, accumulation fp32.
//
// R7: wcvt + 3x(linear,agg) fused into ONE cooperative kernel (grid.sync
// between phases) -- R6 profile showed no kernel >42us but ~19 dispatches
// (launch gaps) and linear's 32B-segment epilogue stores. Linear epilogue now
// stages tiles in LDS and stores 1KB contiguous per wave; agg streams
// (hprev/hout/epack) use nontemporal hints to protect gather cache residency.

#define D_DIM 128
#define SCAN_CHUNK 1024
#define CHUNKS 256         // edge chunks; grid for hist/scatter
#define GROUPS 8
#define GS (CHUNKS / GROUPS)   // 32 chunks per group
#define LDSW 12512         // packed words: 4 bins/word -> 50048 bins >= N

typedef __attribute__((ext_vector_type(8))) short bf16x8;
typedef __attribute__((ext_vector_type(4))) float f32x4;

static __device__ __forceinline__ short f2bf(float f) {
    union { __hip_bfloat16 b; short s; } u;
    u.b = __float2bfloat16(f);
    return u.s;
}
static __device__ __forceinline__ float bf_lo(unsigned p) { return __uint_as_float(p << 16); }
static __device__ __forceinline__ float bf_hi(unsigned p) { return __uint_as_float(p & 0xffff0000u); }

union f2ll { float2 f; long long ll; };

// ---------------- CSR build (no global atomics, packed u8) ------------------

__global__ __launch_bounds__(256) void hist_kernel(const int* __restrict__ ei,
                                                   unsigned* __restrict__ partial_col,
                                                   unsigned* __restrict__ partial_row,
                                                   int E, int CHSZ) {
    __shared__ unsigned hh[LDSW];
    int tid = threadIdx.x;
    int ch = blockIdx.x;
    int docol = (blockIdx.y == 0);
    for (int i = tid; i < LDSW; i += 256) hh[i] = 0u;
    __syncthreads();
    int e0 = ch * CHSZ, e1 = min(e0 + CHSZ, E);
    for (int e = e0 + tid; e < e1; e += 256) {
        int row = ei[e];
        int col = ei[E + e];
        if (row == col) continue;                  // remove_self_loops
        int bin = docol ? col : row;
        atomicAdd(&hh[bin >> 2], 1u << ((bin & 3) * 8));
    }
    __syncthreads();
    unsigned* dst = (docol ? partial_col : partial_row) + (size_t)ch * LDSW;
    for (int i = tid; i < LDSW; i += 256) dst[i] = hh[i];
}

__global__ __launch_bounds__(256) void group_prefix_kernel(
    unsigned* __restrict__ partial_col, const unsigned* __restrict__ partial_row,
    unsigned* __restrict__ gsum_col, unsigned* __restrict__ gsum_row, int NW) {
    int w = blockIdx.x * 256 + threadIdx.x;
    if (w >= NW) return;
    int g = blockIdx.y;
    size_t base = (size_t)(g * GS) * LDSW + w;
    if (blockIdx.z == 0) {
        unsigned run = 0;
#pragma unroll 4
        for (int c = 0; c < GS; c++) {
            unsigned v = partial_col[base + (size_t)c * LDSW];
            partial_col[base + (size_t)c * LDSW] = run;
            run += v;
        }
        gsum_col[g * NW + w] = run;
    } else {
        unsigned run = 0;
#pragma unroll 4
        for (int c = 0; c < GS; c++) run += partial_row[base + (size_t)c * LDSW];
        gsum_row[g * NW + w] = run;
    }
}

__global__ __launch_bounds__(256) void cnt_dis_kernel(
    const unsigned* __restrict__ gsum_col, const unsigned* __restrict__ gsum_row,
    int* __restrict__ col_cnt, float* __restrict__ dis, int* __restrict__ bsum, int NW) {
    __shared__ int wsum[4];
    int w = blockIdx.x * 256 + threadIdx.x;
    int s = 0;
    if (w < NW) {
        unsigned clo = 0, chi = 0, rlo = 0, rhi = 0;
#pragma unroll
        for (int g = 0; g < GROUPS; g++) {
            unsigned wc = gsum_col[g * NW + w];
            unsigned wr = gsum_row[g * NW + w];
            clo += wc & 0x00FF00FFu; chi += (wc >> 8) & 0x00FF00FFu;
            rlo += wr & 0x00FF00FFu; rhi += (wr >> 8) & 0x00FF00FFu;
        }
        int c0 = clo & 0xFFFF, c1 = chi & 0xFFFF, c2 = clo >> 16, c3 = chi >> 16;
        int r0 = rlo & 0xFFFF, r1 = rhi & 0xFFFF, r2 = rlo >> 16, r3 = rhi >> 16;
        ((int4*)col_cnt)[w] = make_int4(c0, c1, c2, c3);
        float4 dv;
        dv.x = (r0 > 0) ? rsqrtf((float)r0) : 0.0f;
        dv.y = (r1 > 0) ? rsqrtf((float)r1) : 0.0f;
        dv.z = (r2 > 0) ? rsqrtf((float)r2) : 0.0f;
        dv.w = (r3 > 0) ? rsqrtf((float)r3) : 0.0f;
        ((float4*)dis)[w] = dv;
        s = c0 + c1 + c2 + c3;
    }
#pragma unroll
    for (int d = 32; d > 0; d >>= 1) s += __shfl_down(s, d, 64);
    int lane = threadIdx.x & 63, wv = threadIdx.x >> 6;
    if (lane == 0) wsum[wv] = s;
    __syncthreads();
    if (threadIdx.x == 0) bsum[blockIdx.x] = wsum[0] + wsum[1] + wsum[2] + wsum[3];
}

__global__ __launch_bounds__(64) void scan_bbase_kernel(const int* __restrict__ bsum,
                                                        int* __restrict__ bbase,
                                                        int* __restrict__ offs,
                                                        int G, int n) {
    int lane = threadIdx.x;
    int v = (lane < G) ? bsum[lane] : 0;
    int s = v;
#pragma unroll
    for (int d = 1; d < 64; d <<= 1) {
        int t = __shfl_up(s, d, 64);
        if (lane >= d) s += t;
    }
    if (lane < G) bbase[lane] = s - v;
    if (lane == 63) offs[n] = s;
}

__global__ __launch_bounds__(256) void scan_final_kernel(const int* __restrict__ cnt,
                                                         const int* __restrict__ bbase,
                                                         int* __restrict__ offs, int n) {
    __shared__ int wsum[4];
    int base = blockIdx.x * SCAN_CHUNK;
    int tid = threadIdx.x;
    const int PT = SCAN_CHUNK / 256;
    int v[PT];
    int s = 0;
#pragma unroll
    for (int i = 0; i < PT; i++) {
        int g = base + tid * PT + i;
        v[i] = (g < n) ? cnt[g] : 0;
        s += v[i];
    }
    int local_sum = s;
    int lane = tid & 63, w = tid >> 6;
#pragma unroll
    for (int d = 1; d < 64; d <<= 1) {
        int t = __shfl_up(s, d, 64);
        if (lane >= d) s += t;
    }
    if (lane == 63) wsum[w] = s;
    __syncthreads();
    int wbase = 0;
    for (int i = 0; i < w; i++) wbase += wsum[i];
    int run = bbase[blockIdx.x] + wbase + (s - local_sum);
#pragma unroll
    for (int i = 0; i < PT; i++) {
        int g = base + tid * PT + i;
        if (g < n) offs[g] = run;
        run += v[i];
    }
}

__global__ __launch_bounds__(256) void group_base_kernel(
    unsigned* __restrict__ partial_col, const unsigned* __restrict__ gsum_col, int NW) {
    int w = blockIdx.x * 256 + threadIdx.x;
    if (w >= NW) return;
    int g = blockIdx.y + 1;
    unsigned gb = 0;
    for (int gp = 0; gp < g; gp++) gb += gsum_col[gp * NW + w];  // <=45/lane, no carry
    size_t base = (size_t)(g * GS) * LDSW + w;
#pragma unroll 4
    for (int c = 0; c < GS; c++) partial_col[base + (size_t)c * LDSW] += gb;
}

__global__ __launch_bounds__(256) void scatter_kernel(const int* __restrict__ ei,
                                                      const float* __restrict__ dis,
                                                      const int* __restrict__ offs,
                                                      const unsigned* __restrict__ chpref,
                                                      int2* __restrict__ epack,
                                                      int E, int CHSZ) {
    __shared__ unsigned cur[LDSW];
    int tid = threadIdx.x;
    int ch = blockIdx.x;
    for (int i = tid; i < LDSW; i += 256) cur[i] = 0u;
    __syncthreads();
    int e0 = ch * CHSZ, e1 = min(e0 + CHSZ, E);
    const unsigned* pf = chpref + (size_t)ch * LDSW;
    for (int e = e0 + tid; e < e1; e += 256) {
        int row = ei[e];
        int col = ei[E + e];
        if (row == col) continue;
        float wgt = dis[row] * dis[col];
        int wd = col >> 2, sh = (col & 3) * 8;
        unsigned old = atomicAdd(&cur[wd], 1u << sh);
        int slot = offs[col] + (int)((pf[wd] >> sh) & 0xFFu) + (int)((old >> sh) & 0xFFu);
        epack[slot] = make_int2(row * (D_DIM / 2), __float_as_int(wgt));
    }
}

// ---------------- fused per-layer cooperative kernel ------------------------

struct LayerParams {
    const float* x;
    const float* W0; const float* W1; const float* W2;
    const float* b0; const float* b1; const float* b2;
    const int* offs;
    const long long* epack;
    unsigned short* Wb;        // 3 * 128*128 bf16
    unsigned short* hWb;       // N * 128 bf16
    float* h;                  // d_out
    int N;
};

// wcvt; then 3x { linear (MFMA 16x16x32, LDS-staged coalesced stores) ;
// grid.sync ; agg (bf16 gather, 8-deep MLP, nontemporal streams) ; grid.sync }
__global__ __launch_bounds__(256, 4) void layers_kernel(LayerParams P) {
    cg::grid_group grid = cg::this_grid();
    __shared__ unsigned short stage[4][16 * 136];   // per-wave 16x128 tile, stride 136

    int tid = threadIdx.x;
    int lane = tid & 63, wv = tid >> 6;
    int m = lane & 15, q = lane >> 4;
    int gthreads = (int)gridDim.x * 256;
    int gtid = (int)blockIdx.x * 256 + tid;
    int nwaves = (int)gridDim.x * 4;
    int gwave = (int)blockIdx.x * 4 + wv;
    int T = (P.N + 15) / 16;

    // phase 0: W -> bf16
    for (int i = gtid; i < 3 * D_DIM * D_DIM; i += gthreads) {
        const float* W = (i < 16384) ? P.W0 : (i < 32768) ? P.W1 : P.W2;
        P.Wb[i] = (unsigned short)f2bf(W[i & 16383]);
    }
    grid.sync();

    const float* hp = P.x;
    for (int l = 0; l < 3; l++) {
        const unsigned short* Wb = P.Wb + l * 16384;
        const float* bias = (l == 0) ? P.b0 : (l == 1) ? P.b1 : P.b2;

        // ---- linear: hWb[r][j] = bf16(b[j] + sum_k hp[r][k]*W[j][k]) ----
        for (int tile = gwave; tile < T; tile += nwaves) {
            int r0 = tile * 16;
            int rload = min(r0 + m, P.N - 1);
            const float4* h4 = (const float4*)hp;
            f32x4 acc[8];
#pragma unroll
            for (int jt = 0; jt < 8; jt++) acc[jt] = (f32x4){0.f, 0.f, 0.f, 0.f};
#pragma unroll
            for (int k0 = 0; k0 < 128; k0 += 32) {
                int c0 = k0 + q * 8;
                float4 x0 = h4[rload * 32 + (c0 >> 2)];
                float4 x1 = h4[rload * 32 + (c0 >> 2) + 1];
                bf16x8 a;
                a[0] = f2bf(x0.x); a[1] = f2bf(x0.y); a[2] = f2bf(x0.z); a[3] = f2bf(x0.w);
                a[4] = f2bf(x1.x); a[5] = f2bf(x1.y); a[6] = f2bf(x1.z); a[7] = f2bf(x1.w);
#pragma unroll
                for (int jt = 0; jt < 8; jt++) {
                    bf16x8 b = *(const bf16x8*)(Wb + (jt * 16 + m) * D_DIM + c0);
                    acc[jt] = __builtin_amdgcn_mfma_f32_16x16x32_bf16(a, b, acc[jt], 0, 0, 0);
                }
            }
            // stage tile in LDS (C/D: col=lane&15, row=q*4+reg), then store
            // 4x contiguous 1KB per wave (R6 did 32x scattered 32B segments).
#pragma unroll
            for (int jt = 0; jt < 8; jt++) {
                float bv = bias[jt * 16 + m];
#pragma unroll
                for (int reg = 0; reg < 4; reg++)
                    stage[wv][(q * 4 + reg) * 136 + jt * 16 + m] =
                        (unsigned short)f2bf(acc[jt][reg] + bv);
            }
#pragma unroll
            for (int t = 0; t < 4; t++) {
                int rl = t * 4 + (lane >> 4);
                int gr = r0 + rl;
                if (gr < P.N) {
                    uint4 v = *(const uint4*)&stage[wv][rl * 136 + (lane & 15) * 8];
                    *(uint4*)&P.hWb[(size_t)gr * D_DIM + (lane & 15) * 8] = v;
                }
            }
        }
        grid.sync();

        // ---- agg: h[v] = hp[v] + relu(sum norm * hWb[row]) ----
        const unsigned* hW2 = (const unsigned*)P.hWb;
        for (int node = gwave; node < P.N; node += nwaves) {
            int beg = P.offs[node];
            int end = P.offs[node + 1];
            float ax8[8], ay8[8];
#pragma unroll
            for (int u = 0; u < 8; u++) { ax8[u] = 0.f; ay8[u] = 0.f; }
            int i = beg;
            for (; i + 8 <= end; i += 8) {
                long long e[8];
                unsigned p[8];
#pragma unroll
                for (int u = 0; u < 8; u++) e[u] = __builtin_nontemporal_load(P.epack + i + u);
#pragma unroll
                for (int u = 0; u < 8; u++) p[u] = hW2[(int)(e[u] & 0xffffffffLL) + lane];
#pragma unroll
                for (int u = 0; u < 8; u++) {
                    float w = __int_as_float((int)(e[u] >> 32));
                    ax8[u] = fmaf(w, bf_lo(p[u]), ax8[u]);
                    ay8[u] = fmaf(w, bf_hi(p[u]), ay8[u]);
                }
            }
            int rem = end - i;
            if (rem & 4) {
                long long e[4];
                unsigned p[4];
#pragma unroll
                for (int u = 0; u < 4; u++) e[u] = __builtin_nontemporal_load(P.epack + i + u);
#pragma unroll
                for (int u = 0; u < 4; u++) p[u] = hW2[(int)(e[u] & 0xffffffffLL) + lane];
#pragma unroll
                for (int u = 0; u < 4; u++) {
                    float w = __int_as_float((int)(e[u] >> 32));
                    ax8[u] = fmaf(w, bf_lo(p[u]), ax8[u]);
                    ay8[u] = fmaf(w, bf_hi(p[u]), ay8[u]);
                }
                i += 4;
            }
            if (rem & 2) {
                long long e0 = __builtin_nontemporal_load(P.epack + i);
                long long e1 = __builtin_nontemporal_load(P.epack + i + 1);
                unsigned p0 = hW2[(int)(e0 & 0xffffffffLL) + lane];
                unsigned p1 = hW2[(int)(e1 & 0xffffffffLL) + lane];
                float w0 = __int_as_float((int)(e0 >> 32));
                float w1 = __int_as_float((int)(e1 >> 32));
                ax8[4] = fmaf(w0, bf_lo(p0), ax8[4]); ay8[4] = fmaf(w0, bf_hi(p0), ay8[4]);
                ax8[5] = fmaf(w1, bf_lo(p1), ax8[5]); ay8[5] = fmaf(w1, bf_hi(p1), ay8[5]);
                i += 2;
            }
            if (rem & 1) {
                long long e0 = __builtin_nontemporal_load(P.epack + i);
                unsigned p0 = hW2[(int)(e0 & 0xffffffffLL) + lane];
                float w0 = __int_as_float((int)(e0 >> 32));
                ax8[6] = fmaf(w0, bf_lo(p0), ax8[6]); ay8[6] = fmaf(w0, bf_hi(p0), ay8[6]);
            }
            float ax = ((ax8[0] + ax8[1]) + (ax8[2] + ax8[3])) + ((ax8[4] + ax8[5]) + (ax8[6] + ax8[7]));
            float ay = ((ay8[0] + ay8[1]) + (ay8[2] + ay8[3])) + ((ay8[4] + ay8[5]) + (ay8[6] + ay8[7]));

            int idx = node * (D_DIM / 2) + lane;
            f2ll hin;
            hin.ll = __builtin_nontemporal_load((const long long*)hp + idx);
            f2ll o;
            o.f.x = hin.f.x + fmaxf(ax, 0.0f);
            o.f.y = hin.f.y + fmaxf(ay, 0.0f);
            __builtin_nontemporal_store(o.ll, (long long*)P.h + idx);
        }
        grid.sync();
        hp = P.h;
    }
}

// ---------------- launch ----------------------------------------------------

static inline size_t align_up(size_t x, size_t a) { return (x + a - 1) & ~(a - 1); }

extern "C" void kernel_launch(void* const* d_in, const int* in_sizes, int n_in,
                              void* d_out, int out_size, void* d_ws, size_t ws_size,
                              hipStream_t stream) {
    const float* x = (const float*)d_in[0];
    const int* ei = (const int*)d_in[1];
    const float* Wl[3] = {(const float*)d_in[2], (const float*)d_in[4], (const float*)d_in[6]};
    const float* bl[3] = {(const float*)d_in[3], (const float*)d_in[5], (const float*)d_in[7]};

    const int N = in_sizes[0] / D_DIM;                 // 50000 (requires N <= 4*LDSW)
    const int E = in_sizes[1] / 2;                     // 800000
    const int NW = N / 4;                              // 12500 packed words
    const int G = (N + SCAN_CHUNK - 1) / SCAN_CHUNK;   // 49
    const int NWB = (NW + 255) / 256;                  // 49 word-blocks
    const int CHSZ = (E + CHUNKS - 1) / CHUNKS;        // 3125

    char* p = (char*)d_ws;
    int* col_cnt = (int*)p;            p += align_up((size_t)N * 4, 256);
    int* offs    = (int*)p;            p += align_up((size_t)(N + 1) * 4, 256);
    float* dis   = (float*)p;          p += align_up((size_t)N * 4, 256);
    int* bsum    = (int*)p;            p += align_up((size_t)64 * 4, 256);
    int* bbase   = (int*)p;            p += align_up((size_t)64 * 4, 256);
    unsigned* partial_col = (unsigned*)p;  p += align_up((size_t)CHUNKS * LDSW * 4, 256);
    unsigned* partial_row = (unsigned*)p;  p += align_up((size_t)CHUNKS * LDSW * 4, 256);
    unsigned* gsum_col = (unsigned*)p; p += align_up((size_t)GROUPS * NW * 4, 256);
    unsigned* gsum_row = (unsigned*)p; p += align_up((size_t)GROUPS * NW * 4, 256);
    unsigned short* Wb = (unsigned short*)p;  p += align_up((size_t)3 * D_DIM * D_DIM * 2, 256);
    int2* epack  = (int2*)p;           p += align_up((size_t)E * 8, 256);
    unsigned short* hWb = (unsigned short*)p;  p += align_up((size_t)N * D_DIM * 2, 256);
    (void)ws_size;

    hist_kernel<<<dim3(CHUNKS, 2), 256, 0, stream>>>(ei, partial_col, partial_row, E, CHSZ);
    group_prefix_kernel<<<dim3(NWB, GROUPS, 2), 256, 0, stream>>>(partial_col, partial_row,
                                                                  gsum_col, gsum_row, NW);
    cnt_dis_kernel<<<NWB, 256, 0, stream>>>(gsum_col, gsum_row, col_cnt, dis, bsum, NW);
    scan_bbase_kernel<<<1, 64, 0, stream>>>(bsum, bbase, offs, G, N);
    scan_final_kernel<<<G, 256, 0, stream>>>(col_cnt, bbase, offs, N);
    group_base_kernel<<<dim3(NWB, GROUPS - 1), 256, 0, stream>>>(partial_col, gsum_col, NW);
    scatter_kernel<<<CHUNKS, 256, 0, stream>>>(ei, dis, offs, partial_col, epack, E, CHSZ);

    int occ = 0;
    hipOccupancyMaxActiveBlocksPerMultiprocessor(&occ, layers_kernel, 256, 0);
    if (occ < 1) occ = 1;
    int lgrid = occ * 256;                  // 256 CUs on MI355X
    if (lgrid > 2048) lgrid = 2048;

    LayerParams prm;
    prm.x = x;
    prm.W0 = Wl[0]; prm.W1 = Wl[1]; prm.W2 = Wl[2];
    prm.b0 = bl[0]; prm.b1 = bl[1]; prm.b2 = bl[2];
    prm.offs = offs;
    prm.epack = (const long long*)epack;
    prm.Wb = Wb;
    prm.hWb = hWb;
    prm.h = (float*)d_out;
    prm.N = N;
    void* kp[] = { &prm };
    hipLaunchCooperativeKernel(layers_kernel, dim3(lgrid), dim3(256), kp, 0, stream);
}

// Round 8
// 316.715 us; speedup vs baseline: 2.8513x; 2.8513x over previous
//
#include <hip/hip_runtime.h>
#include <hip/hip_bf16.h>

// GCN: 3 layers of  h = h + relu( segment_sum( norm * (h@W^T+b)[row], col ) )
// norm[e] = dis[row]*dis[col]*(row!=col), dis[v] = deg_row(v)>0 ? rsqrt(deg) : 0
// N=50000, D=128, E=800000. Harness compares in bf16 space (threshold 0.108):
// hW / GEMM inputs carried in bf16, accumulation fp32.
//
// R8: REVERT of R7's cooperative fusion (grid.sync forces device-scope cache
// flush across the 8 non-coherent XCD L2s every barrier -> 903us, VALUBusy
// 4.8%). Back to R6's separate launches (326us), keeping two safe wins:
//  - linear epilogue stages its 16x128 bf16 tile in LDS and stores 4x1KB
//    contiguous per wave (R6: 32x scattered 32B segments)
//  - epack shrunk 8B -> 4B: row:u16 | norm:bf16 (N < 2^16)

#define D_DIM 128
#define SCAN_CHUNK 1024
#define CHUNKS 256         // edge chunks; grid for hist/scatter (1 block/CU)
#define GROUPS 8
#define GS (CHUNKS / GROUPS)   // 32 chunks per group
#define LDSW 12512         // packed words: 4 bins/word -> 50048 bins >= N

typedef __attribute__((ext_vector_type(8))) short bf16x8;
typedef __attribute__((ext_vector_type(4))) float f32x4;

static __device__ __forceinline__ short f2bf(float f) {
    union { __hip_bfloat16 b; short s; } u;
    u.b = __float2bfloat16(f);
    return u.s;
}
static __device__ __forceinline__ float bf_lo(unsigned p) { return __uint_as_float(p << 16); }
static __device__ __forceinline__ float bf_hi(unsigned p) { return __uint_as_float(p & 0xffff0000u); }

// ---------------- CSR build (no global atomics, packed u8) ------------------

__global__ __launch_bounds__(256) void hist_kernel(const int* __restrict__ ei,
                                                   unsigned* __restrict__ partial_col,
                                                   unsigned* __restrict__ partial_row,
                                                   int E, int CHSZ) {
    __shared__ unsigned hh[LDSW];
    int tid = threadIdx.x;
    int ch = blockIdx.x;
    int docol = (blockIdx.y == 0);
    for (int i = tid; i < LDSW; i += 256) hh[i] = 0u;
    __syncthreads();
    int e0 = ch * CHSZ, e1 = min(e0 + CHSZ, E);
    for (int e = e0 + tid; e < e1; e += 256) {
        int row = ei[e];
        int col = ei[E + e];
        if (row == col) continue;                  // remove_self_loops
        int bin = docol ? col : row;
        atomicAdd(&hh[bin >> 2], 1u << ((bin & 3) * 8));
    }
    __syncthreads();
    unsigned* dst = (docol ? partial_col : partial_row) + (size_t)ch * LDSW;
    for (int i = tid; i < LDSW; i += 256) dst[i] = hh[i];
}

__global__ __launch_bounds__(256) void group_prefix_kernel(
    unsigned* __restrict__ partial_col, const unsigned* __restrict__ partial_row,
    unsigned* __restrict__ gsum_col, unsigned* __restrict__ gsum_row, int NW) {
    int w = blockIdx.x * 256 + threadIdx.x;
    if (w >= NW) return;
    int g = blockIdx.y;
    size_t base = (size_t)(g * GS) * LDSW + w;
    if (blockIdx.z == 0) {
        unsigned run = 0;
#pragma unroll 4
        for (int c = 0; c < GS; c++) {
            unsigned v = partial_col[base + (size_t)c * LDSW];
            partial_col[base + (size_t)c * LDSW] = run;
            run += v;
        }
        gsum_col[g * NW + w] = run;
    } else {
        unsigned run = 0;
#pragma unroll 4
        for (int c = 0; c < GS; c++) run += partial_row[base + (size_t)c * LDSW];
        gsum_row[g * NW + w] = run;
    }
}

__global__ __launch_bounds__(256) void cnt_dis_kernel(
    const unsigned* __restrict__ gsum_col, const unsigned* __restrict__ gsum_row,
    int* __restrict__ col_cnt, float* __restrict__ dis, int* __restrict__ bsum, int NW) {
    __shared__ int wsum[4];
    int w = blockIdx.x * 256 + threadIdx.x;
    int s = 0;
    if (w < NW) {
        unsigned clo = 0, chi = 0, rlo = 0, rhi = 0;
#pragma unroll
        for (int g = 0; g < GROUPS; g++) {
            unsigned wc = gsum_col[g * NW + w];
            unsigned wr = gsum_row[g * NW + w];
            clo += wc & 0x00FF00FFu; chi += (wc >> 8) & 0x00FF00FFu;
            rlo += wr & 0x00FF00FFu; rhi += (wr >> 8) & 0x00FF00FFu;
        }
        int c0 = clo & 0xFFFF, c1 = chi & 0xFFFF, c2 = clo >> 16, c3 = chi >> 16;
        int r0 = rlo & 0xFFFF, r1 = rhi & 0xFFFF, r2 = rlo >> 16, r3 = rhi >> 16;
        ((int4*)col_cnt)[w] = make_int4(c0, c1, c2, c3);
        float4 dv;
        dv.x = (r0 > 0) ? rsqrtf((float)r0) : 0.0f;
        dv.y = (r1 > 0) ? rsqrtf((float)r1) : 0.0f;
        dv.z = (r2 > 0) ? rsqrtf((float)r2) : 0.0f;
        dv.w = (r3 > 0) ? rsqrtf((float)r3) : 0.0f;
        ((float4*)dis)[w] = dv;
        s = c0 + c1 + c2 + c3;
    }
#pragma unroll
    for (int d = 32; d > 0; d >>= 1) s += __shfl_down(s, d, 64);
    int lane = threadIdx.x & 63, wv = threadIdx.x >> 6;
    if (lane == 0) wsum[wv] = s;
    __syncthreads();
    if (threadIdx.x == 0) bsum[blockIdx.x] = wsum[0] + wsum[1] + wsum[2] + wsum[3];
}

__global__ __launch_bounds__(64) void scan_bbase_kernel(const int* __restrict__ bsum,
                                                        int* __restrict__ bbase,
                                                        int* __restrict__ offs,
                                                        int G, int n) {
    int lane = threadIdx.x;
    int v = (lane < G) ? bsum[lane] : 0;
    int s = v;
#pragma unroll
    for (int d = 1; d < 64; d <<= 1) {
        int t = __shfl_up(s, d, 64);
        if (lane >= d) s += t;
    }
    if (lane < G) bbase[lane] = s - v;
    if (lane == 63) offs[n] = s;
}

__global__ __launch_bounds__(256) void scan_final_kernel(const int* __restrict__ cnt,
                                                         const int* __restrict__ bbase,
                                                         int* __restrict__ offs, int n) {
    __shared__ int wsum[4];
    int base = blockIdx.x * SCAN_CHUNK;
    int tid = threadIdx.x;
    const int PT = SCAN_CHUNK / 256;
    int v[PT];
    int s = 0;
#pragma unroll
    for (int i = 0; i < PT; i++) {
        int g = base + tid * PT + i;
        v[i] = (g < n) ? cnt[g] : 0;
        s += v[i];
    }
    int local_sum = s;
    int lane = tid & 63, w = tid >> 6;
#pragma unroll
    for (int d = 1; d < 64; d <<= 1) {
        int t = __shfl_up(s, d, 64);
        if (lane >= d) s += t;
    }
    if (lane == 63) wsum[w] = s;
    __syncthreads();
    int wbase = 0;
    for (int i = 0; i < w; i++) wbase += wsum[i];
    int run = bbase[blockIdx.x] + wbase + (s - local_sum);
#pragma unroll
    for (int i = 0; i < PT; i++) {
        int g = base + tid * PT + i;
        if (g < n) offs[g] = run;
        run += v[i];
    }
}

__global__ __launch_bounds__(256) void group_base_kernel(
    unsigned* __restrict__ partial_col, const unsigned* __restrict__ gsum_col, int NW) {
    int w = blockIdx.x * 256 + threadIdx.x;
    if (w >= NW) return;
    int g = blockIdx.y + 1;
    unsigned gb = 0;
    for (int gp = 0; gp < g; gp++) gb += gsum_col[gp * NW + w];  // <=45/lane, no carry
    size_t base = (size_t)(g * GS) * LDSW + w;
#pragma unroll 4
    for (int c = 0; c < GS; c++) partial_col[base + (size_t)c * LDSW] += gb;
}

// grid (CHUNKS): slot = offs[col] + chunk_prefix_u8[ch][col] + LDS local rank.
// epack entry: row:u16 (low) | norm:bf16 (high) -- 4 bytes.
__global__ __launch_bounds__(256) void scatter_kernel(const int* __restrict__ ei,
                                                      const float* __restrict__ dis,
                                                      const int* __restrict__ offs,
                                                      const unsigned* __restrict__ chpref,
                                                      unsigned* __restrict__ epack,
                                                      int E, int CHSZ) {
    __shared__ unsigned cur[LDSW];
    int tid = threadIdx.x;
    int ch = blockIdx.x;
    for (int i = tid; i < LDSW; i += 256) cur[i] = 0u;
    __syncthreads();
    int e0 = ch * CHSZ, e1 = min(e0 + CHSZ, E);
    const unsigned* pf = chpref + (size_t)ch * LDSW;
    for (int e = e0 + tid; e < e1; e += 256) {
        int row = ei[e];
        int col = ei[E + e];
        if (row == col) continue;
        float wgt = dis[row] * dis[col];
        int wd = col >> 2, sh = (col & 3) * 8;
        unsigned old = atomicAdd(&cur[wd], 1u << sh);
        int slot = offs[col] + (int)((pf[wd] >> sh) & 0xFFu) + (int)((old >> sh) & 0xFFu);
        epack[slot] = (unsigned)row | ((unsigned)(unsigned short)f2bf(wgt) << 16);
    }
}

// W (fp32 row-major 128x128) x3 -> bf16, one launch
__global__ void wcvt_all_kernel(const float* __restrict__ W0, const float* __restrict__ W1,
                                const float* __restrict__ W2, unsigned short* __restrict__ B0,
                                unsigned short* __restrict__ B1, unsigned short* __restrict__ B2) {
    int i = blockIdx.x * blockDim.x + threadIdx.x;
    const float* W = (blockIdx.y == 0) ? W0 : (blockIdx.y == 1) ? W1 : W2;
    unsigned short* B = (blockIdx.y == 0) ? B0 : (blockIdx.y == 1) ? B1 : B2;
    if (i < D_DIM * D_DIM) B[i] = (unsigned short)f2bf(W[i]);
}

// ---------------- per-layer kernels ----------------------------------------

// hWb[r][j] = bf16( b[j] + sum_k h[r][k] * W[j][k] )  via 16x16x32 bf16 MFMA.
// Wave: 16 rows x 128 cols. C/D layout: col=lane&15, row=(lane>>4)*4+reg.
// Epilogue stages the bf16 tile in LDS then stores 4x contiguous 1KB/wave.
__global__ __launch_bounds__(256) void linear_mfma_kernel(
    const float* __restrict__ A, const unsigned short* __restrict__ Wb,
    const float* __restrict__ bias, unsigned short* __restrict__ hWb, int nrows) {
    __shared__ unsigned short stage[4][16 * 136];
    int wave = threadIdx.x >> 6;
    int lane = threadIdx.x & 63;
    int r0 = blockIdx.x * 64 + wave * 16;
    int m = lane & 15, q = lane >> 4;
    int rload = min(r0 + m, nrows - 1);
    const float4* h4 = (const float4*)A;

    f32x4 acc[8];
#pragma unroll
    for (int jt = 0; jt < 8; jt++) acc[jt] = (f32x4){0.f, 0.f, 0.f, 0.f};

#pragma unroll
    for (int k0 = 0; k0 < 128; k0 += 32) {
        int c0 = k0 + q * 8;
        float4 x0 = h4[rload * 32 + (c0 >> 2)];
        float4 x1 = h4[rload * 32 + (c0 >> 2) + 1];
        bf16x8 a;
        a[0] = f2bf(x0.x); a[1] = f2bf(x0.y); a[2] = f2bf(x0.z); a[3] = f2bf(x0.w);
        a[4] = f2bf(x1.x); a[5] = f2bf(x1.y); a[6] = f2bf(x1.z); a[7] = f2bf(x1.w);
#pragma unroll
        for (int jt = 0; jt < 8; jt++) {
            bf16x8 b = *(const bf16x8*)(Wb + (jt * 16 + m) * D_DIM + c0);
            acc[jt] = __builtin_amdgcn_mfma_f32_16x16x32_bf16(a, b, acc[jt], 0, 0, 0);
        }
    }

#pragma unroll
    for (int jt = 0; jt < 8; jt++) {
        float bv = bias[jt * 16 + m];
#pragma unroll
        for (int reg = 0; reg < 4; reg++)
            stage[wave][(q * 4 + reg) * 136 + jt * 16 + m] =
                (unsigned short)f2bf(acc[jt][reg] + bv);
    }
#pragma unroll
    for (int t = 0; t < 4; t++) {
        int rl = t * 4 + (lane >> 4);
        int gr = r0 + rl;
        if (gr < nrows) {
            uint4 v = *(const uint4*)&stage[wave][rl * 136 + (lane & 15) * 8];
            *(uint4*)&hWb[(size_t)gr * D_DIM + (lane & 15) * 8] = v;
        }
    }
}

// one wave per destination node; bf16 payload gather (4B/lane); exact 8/4/2/1
// batches; fp32 acc; fused h_out = h_prev + relu(acc). epack: row|normbf16.
__global__ __launch_bounds__(256) void agg_kernel(const int* __restrict__ offs,
                                                  const unsigned* __restrict__ epack,
                                                  const unsigned int* __restrict__ hW2,
                                                  const float* __restrict__ hprev,
                                                  float* __restrict__ hout, int n_nodes) {
    int node = (int)((blockIdx.x * blockDim.x + threadIdx.x) >> 6);
    int lane = threadIdx.x & 63;
    if (node >= n_nodes) return;

    int beg = offs[node];
    int end = offs[node + 1];

    float ax8[8], ay8[8];
#pragma unroll
    for (int u = 0; u < 8; u++) { ax8[u] = 0.f; ay8[u] = 0.f; }

    int i = beg;
    for (; i + 8 <= end; i += 8) {
        unsigned e[8];
        unsigned p[8];
#pragma unroll
        for (int u = 0; u < 8; u++) e[u] = epack[i + u];
#pragma unroll
        for (int u = 0; u < 8; u++) p[u] = hW2[((e[u] & 0xffffu) << 6) + lane];
#pragma unroll
        for (int u = 0; u < 8; u++) {
            float w = bf_hi(e[u]);
            ax8[u] = fmaf(w, bf_lo(p[u]), ax8[u]);
            ay8[u] = fmaf(w, bf_hi(p[u]), ay8[u]);
        }
    }
    int rem = end - i;
    if (rem & 4) {
        unsigned e[4];
        unsigned p[4];
#pragma unroll
        for (int u = 0; u < 4; u++) e[u] = epack[i + u];
#pragma unroll
        for (int u = 0; u < 4; u++) p[u] = hW2[((e[u] & 0xffffu) << 6) + lane];
#pragma unroll
        for (int u = 0; u < 4; u++) {
            float w = bf_hi(e[u]);
            ax8[u] = fmaf(w, bf_lo(p[u]), ax8[u]);
            ay8[u] = fmaf(w, bf_hi(p[u]), ay8[u]);
        }
        i += 4;
    }
    if (rem & 2) {
        unsigned e0 = epack[i], e1 = epack[i + 1];
        unsigned p0 = hW2[((e0 & 0xffffu) << 6) + lane];
        unsigned p1 = hW2[((e1 & 0xffffu) << 6) + lane];
        float w0 = bf_hi(e0), w1 = bf_hi(e1);
        ax8[4] = fmaf(w0, bf_lo(p0), ax8[4]); ay8[4] = fmaf(w0, bf_hi(p0), ay8[4]);
        ax8[5] = fmaf(w1, bf_lo(p1), ax8[5]); ay8[5] = fmaf(w1, bf_hi(p1), ay8[5]);
        i += 2;
    }
    if (rem & 1) {
        unsigned e0 = epack[i];
        unsigned p0 = hW2[((e0 & 0xffffu) << 6) + lane];
        float w0 = bf_hi(e0);
        ax8[6] = fmaf(w0, bf_lo(p0), ax8[6]); ay8[6] = fmaf(w0, bf_hi(p0), ay8[6]);
    }
    float ax = ((ax8[0] + ax8[1]) + (ax8[2] + ax8[3])) + ((ax8[4] + ax8[5]) + (ax8[6] + ax8[7]));
    float ay = ((ay8[0] + ay8[1]) + (ay8[2] + ay8[3])) + ((ay8[4] + ay8[5]) + (ay8[6] + ay8[7]));

    int idx = node * (D_DIM / 2) + lane;
    float2 hv = ((const float2*)hprev)[idx];
    float2 o;
    o.x = hv.x + fmaxf(ax, 0.0f);
    o.y = hv.y + fmaxf(ay, 0.0f);
    ((float2*)hout)[idx] = o;
}

// ---------------- launch ----------------------------------------------------

static inline size_t align_up(size_t x, size_t a) { return (x + a - 1) & ~(a - 1); }

extern "C" void kernel_launch(void* const* d_in, const int* in_sizes, int n_in,
                              void* d_out, int out_size, void* d_ws, size_t ws_size,
                              hipStream_t stream) {
    const float* x = (const float*)d_in[0];
    const int* ei = (const int*)d_in[1];
    const float* Wl[3] = {(const float*)d_in[2], (const float*)d_in[4], (const float*)d_in[6]};
    const float* bl[3] = {(const float*)d_in[3], (const float*)d_in[5], (const float*)d_in[7]};

    const int N = in_sizes[0] / D_DIM;                 // 50000 (requires N <= 4*LDSW, N < 65536)
    const int E = in_sizes[1] / 2;                     // 800000
    const int NW = N / 4;                              // 12500 packed words
    const int G = (N + SCAN_CHUNK - 1) / SCAN_CHUNK;   // 49
    const int NWB = (NW + 255) / 256;                  // 49 word-blocks
    const int CHSZ = (E + CHUNKS - 1) / CHUNKS;        // 3125

    char* p = (char*)d_ws;
    int* col_cnt = (int*)p;            p += align_up((size_t)N * 4, 256);
    int* offs    = (int*)p;            p += align_up((size_t)(N + 1) * 4, 256);
    float* dis   = (float*)p;          p += align_up((size_t)N * 4, 256);
    int* bsum    = (int*)p;            p += align_up((size_t)64 * 4, 256);
    int* bbase   = (int*)p;            p += align_up((size_t)64 * 4, 256);
    unsigned* partial_col = (unsigned*)p;  p += align_up((size_t)CHUNKS * LDSW * 4, 256);
    unsigned* partial_row = (unsigned*)p;  p += align_up((size_t)CHUNKS * LDSW * 4, 256);
    unsigned* gsum_col = (unsigned*)p; p += align_up((size_t)GROUPS * NW * 4, 256);
    unsigned* gsum_row = (unsigned*)p; p += align_up((size_t)GROUPS * NW * 4, 256);
    unsigned short* Wb[3];
    for (int l = 0; l < 3; l++) { Wb[l] = (unsigned short*)p; p += align_up((size_t)D_DIM * D_DIM * 2, 256); }
    unsigned* epack = (unsigned*)p;    p += align_up((size_t)E * 4, 256);
    unsigned short* hWb = (unsigned short*)p;  p += align_up((size_t)N * D_DIM * 2, 256);
    (void)ws_size;

    hist_kernel<<<dim3(CHUNKS, 2), 256, 0, stream>>>(ei, partial_col, partial_row, E, CHSZ);
    group_prefix_kernel<<<dim3(NWB, GROUPS, 2), 256, 0, stream>>>(partial_col, partial_row,
                                                                  gsum_col, gsum_row, NW);
    cnt_dis_kernel<<<NWB, 256, 0, stream>>>(gsum_col, gsum_row, col_cnt, dis, bsum, NW);
    scan_bbase_kernel<<<1, 64, 0, stream>>>(bsum, bbase, offs, G, N);
    scan_final_kernel<<<G, 256, 0, stream>>>(col_cnt, bbase, offs, N);
    group_base_kernel<<<dim3(NWB, GROUPS - 1), 256, 0, stream>>>(partial_col, gsum_col, NW);
    scatter_kernel<<<CHUNKS, 256, 0, stream>>>(ei, dis, offs, partial_col, epack, E, CHSZ);
    wcvt_all_kernel<<<dim3((D_DIM * D_DIM + 255) / 256, 3), 256, 0, stream>>>(
        Wl[0], Wl[1], Wl[2], Wb[0], Wb[1], Wb[2]);

    const float* hprev = x;
    float* h = (float*)d_out;
    int gemm_blocks = (N + 63) / 64;
    int agg_blocks = (N + 3) / 4;
    for (int l = 0; l < 3; l++) {
        linear_mfma_kernel<<<gemm_blocks, 256, 0, stream>>>(hprev, Wb[l], bl[l], hWb, N);
        agg_kernel<<<agg_blocks, 256, 0, stream>>>(offs, epack, (const unsigned int*)hWb, hprev, h, N);
        hprev = h;
    }
}